// Round 5
// baseline (243.573 us; speedup 1.0000x reference)
//
#include <hip/hip_runtime.h>

#define N_NODES 100000
#define N_EDGES 600000
#define H 128
#define CAP 32                                           // per-receiver slot capacity (P(deg>32)~1e-9)

// two-level bucket build
#define BSHIFT 8
#define NBKT ((N_NODES + 255) / 256)                     // 391 coarse buckets of 256 receivers
#define NREP 4                                           // tail replicas per bucket
#define RCAP 640                                         // entries per replica (mean 384, +13 sigma)

#define NB_FILL 586                                      // 1024 edges/block (4 consecutive per thread)
#define NB_PREP 16
#define NB_CONV4 3125                                    // convert blocks: 1024 float4 each (exact)
#define NB_TOTAL (NB_FILL * 6 + (NB_PREP + NB_CONV4 - NB_FILL * 5))  // 3727

#define BLK_NODES 64
#define N_BLKS ((N_NODES + BLK_NODES - 1) / BLK_NODES)   // 1563

typedef short v8s __attribute__((ext_vector_type(8)));   // 8 bf16 (4 VGPRs)
typedef float v4f __attribute__((ext_vector_type(4)));   // 4 fp32 acc

__device__ __forceinline__ unsigned short f2bf(float f) {
    unsigned int u = __float_as_uint(f);
    u = (u + 0x7fffu + ((u >> 16) & 1u)) >> 16;   // round-nearest-even
    return (unsigned short)u;
}
__device__ __forceinline__ unsigned int pack2bf(float a, float b) {
    return (unsigned int)f2bf(a) | ((unsigned int)f2bf(b) << 16);
}
__device__ __forceinline__ void accum8(float* a, uint4 u) {
    a[0] += __uint_as_float(u.x << 16);
    a[1] += __uint_as_float(u.x & 0xffff0000u);
    a[2] += __uint_as_float(u.y << 16);
    a[3] += __uint_as_float(u.y & 0xffff0000u);
    a[4] += __uint_as_float(u.z << 16);
    a[5] += __uint_as_float(u.z & 0xffff0000u);
    a[6] += __uint_as_float(u.w << 16);
    a[7] += __uint_as_float(u.w & 0xffff0000u);
}

// ---------------------------------------------------------------------------
// Prep (one dispatch, role by blockIdx). FILL interleaved every 6th block so
// CONV's streaming BW hides FILL latency (R3 +8us, kept).
// R5 change: FILL no longer builds per-receiver slots. It scatters each edge
// as a packed 4B record (s<<8 | r&255) into one of NBKT*NREP=1564 replica
// tails. The atomicAdd now targets 1564 HOT counters (line-resident at the
// coherence point) instead of 600k scattered lines, and the data store is
// CONTIGUOUS within a tail (full-line DRAM writes, 2.4MB) instead of 600k
// scattered 4B NT stores (which amplified WRITE_SIZE by ~35MB).
// Replica = fill-block & 3: with blockIdx%8 -> XCD round-robin, each replica
// is written by ~2 XCDs (less cross-XCD line merging).
// ---------------------------------------------------------------------------
__global__ __launch_bounds__(256) void prep_fused_kernel(
    const float* __restrict__ x, unsigned int* __restrict__ xb4,
    const float* __restrict__ Ws, const float* __restrict__ Wm,
    unsigned short* __restrict__ Bperm,
    const int* __restrict__ senders, const int* __restrict__ receivers,
    int* __restrict__ tails, unsigned int* __restrict__ lists)
{
    int b = blockIdx.x;
    bool isfill = (b % 6 == 0) && (b / 6 < NB_FILL);
    if (isfill) {
        int fb = b / 6;
        int rep = fb & (NREP - 1);
        int tid = fb * 256 + threadIdx.x;                // edge quad index
        if (tid < N_EDGES / 4) {                         // 150000, exact
            int4 r4 = ((const int4*)receivers)[tid];
            int4 s4 = ((const int4*)senders)[tid];
            int r[4] = {r4.x, r4.y, r4.z, r4.w};
            int s[4] = {s4.x, s4.y, s4.z, s4.w};
#pragma unroll
            for (int k = 0; k < 4; ++k) {
                int bk = r[k] >> BSHIFT;
                int tl = bk * NREP + rep;
                int pos = atomicAdd(&tails[tl], 1);
                if (pos < RCAP)
                    lists[(size_t)tl * RCAP + pos] =
                        ((unsigned int)s[k] << BSHIFT) | (unsigned int)(r[k] & 255);
            }
        }
    } else {
        int o = (b < NB_FILL * 6) ? (b - b / 6 - 1) : (b - NB_FILL);
        if (o < NB_PREP) {
            // B-fragment permute: frag f=(kstep*8+ntile)*64+lane holds
            // B[k=kstep*32+q*8+j][n=ntile*16+(lane&15)], B=[Ws;Wm] (K=256,N=128)
            int t = o * 256 + threadIdx.x; // 0..4095
            int kstep = t >> 9;
            int ntile = (t >> 6) & 7;
            int lane  = t & 63;
            int q = lane >> 4;
            int n = ntile * 16 + (lane & 15);
#pragma unroll
            for (int j = 0; j < 8; ++j) {
                int k = kstep * 32 + q * 8 + j;
                float v = (k < H) ? Ws[k * H + n] : Wm[(k - H) * H + n];
                Bperm[(size_t)t * 8 + j] = f2bf(v);
            }
        } else {
            int base = (o - NB_PREP) * 1024 + threadIdx.x;
#pragma unroll
            for (int k = 0; k < 4; ++k) {
                int i = base + k * 256;                // float4 index
                float4 v = ((const float4*)x)[i];
                uint2 ov;
                ov.x = pack2bf(v.x, v.y);
                ov.y = pack2bf(v.z, v.w);
                ((uint2*)xb4)[i] = ov;
            }
        }
    }
}

// ---------------------------------------------------------------------------
// Level-2 placement: one block per coarse bucket (256 receivers). Reads the
// bucket's 4 replica lists (~1530 edges, coalesced), places each edge via an
// LDS atomic on the fine counter (cheap), stores sender into slots - the
// scattered 4B stores now land inside ONE 32KB region per block (single-XCD
// L2-local, clean full-line write-back). Finally writes cnt for all 256
// receivers (coalesced) -> the 400KB cnt memset is eliminated.
// ---------------------------------------------------------------------------
__global__ __launch_bounds__(256) void place_kernel(
    const int* __restrict__ tails, const unsigned int* __restrict__ lists,
    int* __restrict__ cnt, int* __restrict__ slots)
{
    __shared__ int fc[256];
    const int pb = blockIdx.x;                 // bucket id 0..NBKT-1
    const int tid = threadIdx.x;
    fc[tid] = 0;
    __syncthreads();

    const int base_rid = pb << BSHIFT;
#pragma unroll
    for (int rep = 0; rep < NREP; ++rep) {
        int tl = tails[pb * NREP + rep];
        if (tl > RCAP) tl = RCAP;
        const unsigned int* lp = lists + (size_t)(pb * NREP + rep) * RCAP;
        for (int i = tid; i < tl; i += 256) {
            unsigned int e = lp[i];
            int rl = (int)(e & 255u);
            int s  = (int)(e >> BSHIFT);
            int pos = atomicAdd(&fc[rl], 1);
            if (pos < CAP) slots[(size_t)(base_rid + rl) * CAP + pos] = s;
        }
    }
    __syncthreads();
    int rid = base_rid + tid;
    if (rid < N_NODES) cnt[rid] = fc[tid];
}

// ---------------------------------------------------------------------------
// Fused gather + MFMA GEMM — unchanged from R4 (512 threads, 8 waves, 64-node
// tile, 33.3KB LDS -> 4 blocks/CU = 32 waves/CU = 100% of slots; R4 counter-
// proven improvement: gather dropped below 47us).
// ---------------------------------------------------------------------------
__global__ __launch_bounds__(512) void gather_gemm_kernel(
    const unsigned short* __restrict__ xb,
    const int* __restrict__ cnt,
    const int* __restrict__ slots,
    const unsigned short* __restrict__ Bperm,
    const float* __restrict__ bias,
    float* __restrict__ out)
{
    __shared__ unsigned short tile[2][16][65][8];   // ~32.5 KB, buf0=x buf1=agg

    const int t = threadIdx.x;
    const int w = t >> 6;              // 0..7
    const int lane = t & 63;
    const int node_base = blockIdx.x * BLK_NODES;
    const int sub = (lane >> 4) & 3;   // node within group of 4
    const int li  = lane & 15;         // column chunk (8 bf16 = 16 B)

    // ---- Phase A: gather + stage ----
    for (int g = 0; g < 2; ++g) {
        int nl = w * 8 + g * 4 + sub;              // node_local 0..63
        int node = node_base + nl;
        float a[8];
#pragma unroll
        for (int i = 0; i < 8; ++i) a[i] = 0.f;
        int d_true = 0;
        uint4 xcopy = make_uint4(0, 0, 0, 0);
        if (node < N_NODES) {
            xcopy = *(const uint4*)(xb + (size_t)node * H + li * 8);
            d_true = cnt[node];
            int d = d_true < CAP ? d_true : CAP;
            const int* sl = slots + node * CAP;    // 128B-aligned
            int e = 0;
            for (; e + 3 < d; e += 4) {
                int4 i4 = *(const int4*)&sl[e];    // e%4==0 -> 16B aligned
                uint4 u0 = *(const uint4*)(xb + (size_t)i4.x * H + li * 8);
                uint4 u1 = *(const uint4*)(xb + (size_t)i4.y * H + li * 8);
                uint4 u2 = *(const uint4*)(xb + (size_t)i4.z * H + li * 8);
                uint4 u3 = *(const uint4*)(xb + (size_t)i4.w * H + li * 8);
                accum8(a, u0);
                accum8(a, u1);
                accum8(a, u2);
                accum8(a, u3);
            }
            for (; e < d; ++e) {
                uint4 u0 = *(const uint4*)(xb + (size_t)sl[e] * H + li * 8);
                accum8(a, u0);
            }
        }
        float inv = 1.0f / fmaxf((float)d_true, 1.0f);
        uint4 o;
        o.x = pack2bf(a[0] * inv, a[1] * inv);
        o.y = pack2bf(a[2] * inv, a[3] * inv);
        o.z = pack2bf(a[4] * inv, a[5] * inv);
        o.w = pack2bf(a[6] * inv, a[7] * inv);
        *(uint4*)&tile[0][li][nl][0] = xcopy;
        *(uint4*)&tile[1][li][nl][0] = o;
    }
    __syncthreads();

    // ---- Phase B: GEMM, wave w owns n-tile w ----
    const int q  = lane >> 4;
    const int mr = lane & 15;

    v4f acc[4];
    {
        float bv = bias[w * 16 + mr];
#pragma unroll
        for (int s = 0; s < 4; ++s) acc[s] = (v4f){bv, bv, bv, bv};
    }

    const v8s* bp = (const v8s*)Bperm;
#pragma unroll
    for (int ks = 0; ks < 8; ++ks) {
        int buf = ks >> 2;                 // 0: x-part (K 0..127), 1: agg-part
        int lic = (ks & 3) * 4 + q;        // chunk holding cols [ks*32+q*8, +8)
        v8s a[4];
#pragma unroll
        for (int s = 0; s < 4; ++s)
            a[s] = *(const v8s*)&tile[buf][lic][s * 16 + mr][0];
        v8s bfrag = bp[(ks * 8 + w) * 64 + lane];
#pragma unroll
        for (int s = 0; s < 4; ++s)
            acc[s] = __builtin_amdgcn_mfma_f32_16x16x32_bf16(a[s], bfrag, acc[s], 0, 0, 0);
    }

    // ---- epilogue: bias already in acc; ReLU + store ----
#pragma unroll
    for (int s = 0; s < 4; ++s) {
#pragma unroll
        for (int r = 0; r < 4; ++r) {
            int row = node_base + s * 16 + q * 4 + r;
            if (row < N_NODES)
                out[(size_t)row * H + w * 16 + mr] = fmaxf(acc[s][r], 0.f);
        }
    }
}

extern "C" void kernel_launch(void* const* d_in, const int* in_sizes, int n_in,
                              void* d_out, int out_size, void* d_ws, size_t ws_size,
                              hipStream_t stream) {
    const float* x        = (const float*)d_in[0];
    const int*   senders  = (const int*)d_in[1];
    const int*   receivers= (const int*)d_in[2];
    const float* Ws       = (const float*)d_in[3];
    const float* Wm       = (const float*)d_in[4];
    const float* bias     = (const float*)d_in[5];
    float*       out      = (float*)d_out;

    // workspace layout (~42.9 MB)
    char* p = (char*)d_ws;
    unsigned short* xb    = (unsigned short*)p; p += (size_t)N_NODES * H * sizeof(unsigned short); // 25.6 MB
    unsigned short* Bperm = (unsigned short*)p; p += (size_t)256 * H * sizeof(unsigned short);     // 64 KB
    int* cnt   = (int*)p; p += (size_t)N_NODES * sizeof(int);                                      // 0.4 MB
    int* slots = (int*)p; p += (size_t)N_NODES * CAP * sizeof(int);                                // 12.8 MB
    int* tails = (int*)p; p += (size_t)NBKT * NREP * sizeof(int);                                  // 6.2 KB
    unsigned int* lists = (unsigned int*)p; p += (size_t)NBKT * NREP * RCAP * sizeof(unsigned int);// 4.0 MB

    hipMemsetAsync(tails, 0, (size_t)NBKT * NREP * sizeof(int), stream);

    prep_fused_kernel<<<NB_TOTAL, 256, 0, stream>>>(
        x, (unsigned int*)xb, Ws, Wm, Bperm, senders, receivers, tails, lists);
    place_kernel<<<NBKT, 256, 0, stream>>>(tails, lists, cnt, slots);
    gather_gemm_kernel<<<N_BLKS, 512, 0, stream>>>(xb, cnt, slots, Bperm, bias, out);
}